// Round 1
// baseline (196.797 us; speedup 1.0000x reference)
//
#include <hip/hip_runtime.h>
#include <stdint.h>

// RhymeLoss: mean over b in [0,4096), pairs i<j in [0,32) of
//   same(i,j) ? 1 - cos(u_i,u_j) : relu(cos(u_i,u_j) - 0.5)
//
// R10: ONE BATCH PER WAVE. Post-mortem of R9's counters: the top-5
// dispatches are all harness fillBufferAligned at ~77 us (512 MiB poison
// fills inside the timed graph, ~154 us fixed) -- our kernel is <76.5 us,
// so the controllable budget is only ~36 us of the 190. R1-R9's plateau
// was the poison floor, not atomics.
//
// Within the ~36 us: R9's 4-way K-split pays 3 KiB of LDS partials + two
// __syncthreads per block, then a wave-0-only epilogue (waves 1-3 idle).
// R10 gives each wave its own batch with the FULL K=256: zero
// __syncthreads, zero inter-wave traffic, epilogues parallel across
// waves, fully-unrolled K-loop for deep load prefetch. Grid = 1024 blocks
// (4 batches/block, 128 KiB contiguous) -- entire grid co-resident in one
// dispatch. Kernel B (4096-partial reduce) unchanged from R9.

typedef short bf16x8 __attribute__((ext_vector_type(8)));   // 8 bf16 (4 VGPRs)
typedef float f32x4  __attribute__((ext_vector_type(4)));

#define MARGIN 0.5f
#define EPS_NORM 1e-8f
#define NPAIR_INV (1.0f / 2031616.0f)   // 1 / (4096 * 496)

// fp32 -> bf16 round-to-nearest-even (inputs are finite, no NaN handling)
static __device__ __forceinline__ short f2bf(float f) {
    unsigned u = __float_as_uint(f);
    u += 0x7fffu + ((u >> 16) & 1u);
    return (short)(u >> 16);
}

__global__ __launch_bounds__(256, 8) void rhyme_loss_kernel(
    const float* __restrict__ emb,   // [4096][32][256] fp32
    const int*   __restrict__ sch,   // [4096][32] int32
    float*       __restrict__ part)  // [4096] fp32 per-batch partial sums
{
    // Per-wave private LDS scratch (no cross-wave sharing -> no syncthreads).
    __shared__ float s_diag[4][32];
    __shared__ float s_inv[4][32];
    __shared__ int   s_sch[4][32];

    const int t    = threadIdx.x;
    const int wv   = t >> 6;            // wave 0..3 = which batch of this block
    const int lane = t & 63;
    const int b    = (blockIdx.x << 2) | wv;   // one batch per WAVE

    const int q = lane >> 4;            // k-slot 0..3 -> k-offset q*8 within each 32-chunk
    const int c = lane & 15;            // fragment row (= C col)

    if (lane < 32)                      // scheme, coalesced dwords, wave-private
        s_sch[wv][lane] = sch[(size_t)b * 32 + lane];
    __builtin_amdgcn_wave_barrier();    // keep the write ahead of epilogue reads

    // Lane's source rows: c and 16+c, FULL K. Per 32-chunk the lane's 8
    // floats are contiguous at [kc + q*8, kc + q*8 + 8).
    const float* base0 = emb + (size_t)b * 8192 + (size_t)c * 256 + q * 8;
    const float* base1 = base0 + 16 * 256;

    f32x4 acc00 = {0.f, 0.f, 0.f, 0.f};   // rows 0-15  x cols 0-15
    f32x4 acc01 = {0.f, 0.f, 0.f, 0.f};   // rows 0-15  x cols 16-31
    f32x4 acc11 = {0.f, 0.f, 0.f, 0.f};   // rows 16-31 x cols 16-31
    // (tile 10 is the i>j mirror of 01 -> never needed)

    #pragma unroll
    for (int kc = 0; kc < 256; kc += 32) {
        float4 a0 = *(const float4*)(base0 + kc);
        float4 a1 = *(const float4*)(base0 + kc + 4);
        float4 b0 = *(const float4*)(base1 + kc);
        float4 b1 = *(const float4*)(base1 + kc + 4);

        bf16x8 f0, f1;
        f0[0] = f2bf(a0.x); f0[1] = f2bf(a0.y); f0[2] = f2bf(a0.z); f0[3] = f2bf(a0.w);
        f0[4] = f2bf(a1.x); f0[5] = f2bf(a1.y); f0[6] = f2bf(a1.z); f0[7] = f2bf(a1.w);
        f1[0] = f2bf(b0.x); f1[1] = f2bf(b0.y); f1[2] = f2bf(b0.z); f1[3] = f2bf(b0.w);
        f1[4] = f2bf(b1.x); f1[5] = f2bf(b1.y); f1[6] = f2bf(b1.z); f1[7] = f2bf(b1.w);

        // A-frag and B-frag of a gram share the same per-lane data.
        acc00 = __builtin_amdgcn_mfma_f32_16x16x32_bf16(f0, f0, acc00, 0, 0, 0);
        acc01 = __builtin_amdgcn_mfma_f32_16x16x32_bf16(f0, f1, acc01, 0, 0, 0);
        acc11 = __builtin_amdgcn_mfma_f32_16x16x32_bf16(f1, f1, acc11, 0, 0, 0);
    }

    // ---- Epilogue: per-wave, all four waves in parallel ----
    // C/D layout (m89-verified): col = lane&15, row = (lane>>4)*4 + reg.
    // Diagonal of tiles 00/11: row==col -> reg = c - 4*q when in [0,4).
    const int dreg = c - 4 * q;
    if (dreg >= 0 && dreg < 4) {
        s_diag[wv][c]      = acc00[dreg];   // ||u_c||^2
        s_diag[wv][16 + c] = acc11[dreg];   // ||u_{16+c}||^2
    }
    // Intra-wave producer->consumer through LDS (R7-proven pattern).
    __builtin_amdgcn_wave_barrier();
    if (lane < 32)
        s_inv[wv][lane] = 1.0f / fmaxf(sqrtf(s_diag[wv][lane]), EPS_NORM);
    __builtin_amdgcn_wave_barrier();

    const float invj0 = s_inv[wv][c];
    const float invj1 = s_inv[wv][16 + c];
    const int   sj0   = s_sch[wv][c];
    const int   sj1   = s_sch[wv][16 + c];

    float sum = 0.0f;
    #pragma unroll
    for (int r = 0; r < 4; ++r) {
        const int   i0    = q * 4 + r;
        const float inv_i = s_inv[wv][i0];
        const int   si    = s_sch[wv][i0];

        // tile 01: i = i0 (<16), j = 16+c  -> always i<j
        {
            float sim = acc01[r] * inv_i * invj1;
            sum += (si == sj1) ? (1.0f - sim) : fmaxf(sim - MARGIN, 0.0f);
        }
        if (i0 < c) {
            // tile 00: i = i0, j = c
            float sim = acc00[r] * inv_i * invj0;
            sum += (si == sj0) ? (1.0f - sim) : fmaxf(sim - MARGIN, 0.0f);
            // tile 11: i = 16+i0, j = 16+c
            float sim2 = acc11[r] * s_inv[wv][16 + i0] * invj1;
            sum += (s_sch[wv][16 + i0] == sj1) ? (1.0f - sim2)
                                               : fmaxf(sim2 - MARGIN, 0.0f);
        }
    }

    // wave-64 reduction
    #pragma unroll
    for (int off = 32; off > 0; off >>= 1)
        sum += __shfl_down(sum, off, 64);

    // Contention-free: one plain store per batch.
    if (lane == 0)
        part[b] = sum;
}

__global__ __launch_bounds__(256) void reduce_kernel(
    const float* __restrict__ part,  // [4096]
    float*       __restrict__ out)   // [1]
{
    __shared__ float s[4];
    const int t = threadIdx.x;
    float sum = 0.0f;
    const float4* p4 = (const float4*)part;   // 1024 float4
    #pragma unroll
    for (int i = 0; i < 4; ++i) {
        float4 v = p4[t + 256 * i];
        sum += (v.x + v.y) + (v.z + v.w);
    }
    #pragma unroll
    for (int off = 32; off > 0; off >>= 1)
        sum += __shfl_down(sum, off, 64);
    if ((t & 63) == 0) s[t >> 6] = sum;
    __syncthreads();
    if (t == 0)
        out[0] = ((s[0] + s[1]) + (s[2] + s[3])) * NPAIR_INV;
}

extern "C" void kernel_launch(void* const* d_in, const int* in_sizes, int n_in,
                              void* d_out, int out_size, void* d_ws, size_t ws_size,
                              hipStream_t stream) {
    const float* emb  = (const float*)d_in[0];
    const int*   sch  = (const int*)d_in[1];
    float*       out  = (float*)d_out;
    float*       part = (float*)d_ws;    // 4096 floats = 16 KiB scratch

    rhyme_loss_kernel<<<dim3(1024), dim3(256), 0, stream>>>(emb, sch, part);
    reduce_kernel<<<dim3(1), dim3(256), 0, stream>>>(part, out);
}

// Round 2
// 193.217 us; speedup vs baseline: 1.0185x; 1.0185x over previous
//
#include <hip/hip_runtime.h>
#include <stdint.h>

// RhymeLoss: mean over b in [0,4096), pairs i<j in [0,32) of
//   same(i,j) ? 1 - cos(u_i,u_j) : relu(cos(u_i,u_j) - 0.5)
//
// R11: R10 (one batch per wave, zero block barriers) with the VGPR
// strangle removed. R10 post-mortem: grid is 1024 blocks -> 4 blocks/CU
// -> only 4 waves/SIMD no matter what, yet __launch_bounds__(256,8)
// capped the allocator at 64 VGPRs -- the fully-unrolled K=256 loop
// couldn't keep loads in flight, so waves ran load->vmcnt(0)->convert->
// MFMA serial chains with too little TLP to hide ~900cy HBM latency.
// Fix: (1) __launch_bounds__(256,4) = 128 VGPRs, matching the occupancy
// the grid actually delivers; (2) explicit 2-stage software pipeline --
// iteration k+1's four float4 loads issue before iteration k's
// convert+MFMA, so fetch overlaps compute. Numerics bit-identical to R10
// (same accumulation order). Kernel B unchanged.
//
// Fixed costs (harness, not ours): 2x 512 MiB poison fills ~154 us inside
// the timed graph + tiny reset memsets. Controllable budget ~30 us;
// 128 MiB read floor ~19-21 us at the ~7 TB/s the fills demonstrate.

typedef short bf16x8 __attribute__((ext_vector_type(8)));   // 8 bf16 (4 VGPRs)
typedef float f32x4  __attribute__((ext_vector_type(4)));

#define MARGIN 0.5f
#define EPS_NORM 1e-8f
#define NPAIR_INV (1.0f / 2031616.0f)   // 1 / (4096 * 496)

// fp32 -> bf16 round-to-nearest-even (inputs are finite, no NaN handling)
static __device__ __forceinline__ short f2bf(float f) {
    unsigned u = __float_as_uint(f);
    u += 0x7fffu + ((u >> 16) & 1u);
    return (short)(u >> 16);
}

__global__ __launch_bounds__(256, 4) void rhyme_loss_kernel(
    const float* __restrict__ emb,   // [4096][32][256] fp32
    const int*   __restrict__ sch,   // [4096][32] int32
    float*       __restrict__ part)  // [4096] fp32 per-batch partial sums
{
    // Per-wave private LDS scratch (no cross-wave sharing -> no syncthreads).
    __shared__ float s_diag[4][32];
    __shared__ float s_inv[4][32];
    __shared__ int   s_sch[4][32];

    const int t    = threadIdx.x;
    const int wv   = t >> 6;            // wave 0..3 = which batch of this block
    const int lane = t & 63;
    const int b    = (blockIdx.x << 2) | wv;   // one batch per WAVE

    const int q = lane >> 4;            // k-slot 0..3 -> k-offset q*8 within each 32-chunk
    const int c = lane & 15;            // fragment row (= C col)

    if (lane < 32)                      // scheme, coalesced dwords, wave-private
        s_sch[wv][lane] = sch[(size_t)b * 32 + lane];
    __builtin_amdgcn_wave_barrier();    // keep the write ahead of epilogue reads

    // Lane's source rows: c and 16+c, FULL K. Per 32-chunk the lane's 8
    // floats are contiguous at [kc + q*8, kc + q*8 + 8).
    const float* base0 = emb + (size_t)b * 8192 + (size_t)c * 256 + q * 8;
    const float* base1 = base0 + 16 * 256;

    f32x4 acc00 = {0.f, 0.f, 0.f, 0.f};   // rows 0-15  x cols 0-15
    f32x4 acc01 = {0.f, 0.f, 0.f, 0.f};   // rows 0-15  x cols 16-31
    f32x4 acc11 = {0.f, 0.f, 0.f, 0.f};   // rows 16-31 x cols 16-31
    // (tile 10 is the i>j mirror of 01 -> never needed)

    // 2-stage software pipeline: stage 0 primed here, each iteration
    // issues iteration k+1's loads before converting/MFMA-ing iteration k.
    float4 a0 = *(const float4*)(base0);
    float4 a1 = *(const float4*)(base0 + 4);
    float4 b0 = *(const float4*)(base1);
    float4 b1 = *(const float4*)(base1 + 4);

    #pragma unroll
    for (int kc = 0; kc < 256; kc += 32) {
        float4 na0, na1, nb0, nb1;
        if (kc < 224) {   // compile-time after unroll
            na0 = *(const float4*)(base0 + kc + 32);
            na1 = *(const float4*)(base0 + kc + 36);
            nb0 = *(const float4*)(base1 + kc + 32);
            nb1 = *(const float4*)(base1 + kc + 36);
        }

        bf16x8 f0, f1;
        f0[0] = f2bf(a0.x); f0[1] = f2bf(a0.y); f0[2] = f2bf(a0.z); f0[3] = f2bf(a0.w);
        f0[4] = f2bf(a1.x); f0[5] = f2bf(a1.y); f0[6] = f2bf(a1.z); f0[7] = f2bf(a1.w);
        f1[0] = f2bf(b0.x); f1[1] = f2bf(b0.y); f1[2] = f2bf(b0.z); f1[3] = f2bf(b0.w);
        f1[4] = f2bf(b1.x); f1[5] = f2bf(b1.y); f1[6] = f2bf(b1.z); f1[7] = f2bf(b1.w);

        // A-frag and B-frag of a gram share the same per-lane data.
        acc00 = __builtin_amdgcn_mfma_f32_16x16x32_bf16(f0, f0, acc00, 0, 0, 0);
        acc01 = __builtin_amdgcn_mfma_f32_16x16x32_bf16(f0, f1, acc01, 0, 0, 0);
        acc11 = __builtin_amdgcn_mfma_f32_16x16x32_bf16(f1, f1, acc11, 0, 0, 0);

        if (kc < 224) {
            a0 = na0; a1 = na1; b0 = nb0; b1 = nb1;
        }
    }

    // ---- Epilogue: per-wave, all four waves in parallel ----
    // C/D layout (m89-verified): col = lane&15, row = (lane>>4)*4 + reg.
    // Diagonal of tiles 00/11: row==col -> reg = c - 4*q when in [0,4).
    const int dreg = c - 4 * q;
    if (dreg >= 0 && dreg < 4) {
        s_diag[wv][c]      = acc00[dreg];   // ||u_c||^2
        s_diag[wv][16 + c] = acc11[dreg];   // ||u_{16+c}||^2
    }
    // Intra-wave producer->consumer through LDS (R7-proven pattern).
    __builtin_amdgcn_wave_barrier();
    if (lane < 32)
        s_inv[wv][lane] = 1.0f / fmaxf(sqrtf(s_diag[wv][lane]), EPS_NORM);
    __builtin_amdgcn_wave_barrier();

    const float invj0 = s_inv[wv][c];
    const float invj1 = s_inv[wv][16 + c];
    const int   sj0   = s_sch[wv][c];
    const int   sj1   = s_sch[wv][16 + c];

    float sum = 0.0f;
    #pragma unroll
    for (int r = 0; r < 4; ++r) {
        const int   i0    = q * 4 + r;
        const float inv_i = s_inv[wv][i0];
        const int   si    = s_sch[wv][i0];

        // tile 01: i = i0 (<16), j = 16+c  -> always i<j
        {
            float sim = acc01[r] * inv_i * invj1;
            sum += (si == sj1) ? (1.0f - sim) : fmaxf(sim - MARGIN, 0.0f);
        }
        if (i0 < c) {
            // tile 00: i = i0, j = c
            float sim = acc00[r] * inv_i * invj0;
            sum += (si == sj0) ? (1.0f - sim) : fmaxf(sim - MARGIN, 0.0f);
            // tile 11: i = 16+i0, j = 16+c
            float sim2 = acc11[r] * s_inv[wv][16 + i0] * invj1;
            sum += (s_sch[wv][16 + i0] == sj1) ? (1.0f - sim2)
                                               : fmaxf(sim2 - MARGIN, 0.0f);
        }
    }

    // wave-64 reduction
    #pragma unroll
    for (int off = 32; off > 0; off >>= 1)
        sum += __shfl_down(sum, off, 64);

    // Contention-free: one plain store per batch.
    if (lane == 0)
        part[b] = sum;
}

__global__ __launch_bounds__(256) void reduce_kernel(
    const float* __restrict__ part,  // [4096]
    float*       __restrict__ out)   // [1]
{
    __shared__ float s[4];
    const int t = threadIdx.x;
    float sum = 0.0f;
    const float4* p4 = (const float4*)part;   // 1024 float4
    #pragma unroll
    for (int i = 0; i < 4; ++i) {
        float4 v = p4[t + 256 * i];
        sum += (v.x + v.y) + (v.z + v.w);
    }
    #pragma unroll
    for (int off = 32; off > 0; off >>= 1)
        sum += __shfl_down(sum, off, 64);
    if ((t & 63) == 0) s[t >> 6] = sum;
    __syncthreads();
    if (t == 0)
        out[0] = ((s[0] + s[1]) + (s[2] + s[3])) * NPAIR_INV;
}

extern "C" void kernel_launch(void* const* d_in, const int* in_sizes, int n_in,
                              void* d_out, int out_size, void* d_ws, size_t ws_size,
                              hipStream_t stream) {
    const float* emb  = (const float*)d_in[0];
    const int*   sch  = (const int*)d_in[1];
    float*       out  = (float*)d_out;
    float*       part = (float*)d_ws;    // 4096 floats = 16 KiB scratch

    rhyme_loss_kernel<<<dim3(1024), dim3(256), 0, stream>>>(emb, sch, part);
    reduce_kernel<<<dim3(1), dim3(256), 0, stream>>>(part, out);
}